// Round 1
// baseline (360.078 us; speedup 1.0000x reference)
//
#include <hip/hip_runtime.h>

#define IN_FT 256
#define OUT_FT 64

// ---------------------------------------------------------------------------
// GEMM: fts[N,64] = seq[N,256] @ W[64,256]^T   (fp32 vector ALU; no fp32 MFMA)
// Block = 256 threads computes 64 nodes x 64 feats; 4x4 register micro-tile.
// ---------------------------------------------------------------------------
constexpr int BN  = 64;   // nodes per block
constexpr int BK  = 32;   // k-chunk
constexpr int LDT = 68;   // padded LDS stride (floats): 16B-aligned rows, <=4-way bank conflict

__global__ __launch_bounds__(256) void gemm_kernel(
    const float* __restrict__ seq, const float* __restrict__ W,
    float* __restrict__ fts, int N)
{
    __shared__ float As[BK][LDT];   // [k][node]
    __shared__ float Bs[BK][LDT];   // [k][feat]
    const int t  = (int)threadIdx.x;
    const int tx = t & 15;          // feature quad
    const int ty = t >> 4;          // node quad
    const int nodeBase = (int)blockIdx.x * BN;

    float acc[4][4];
#pragma unroll
    for (int i = 0; i < 4; ++i)
#pragma unroll
        for (int j = 0; j < 4; ++j) acc[i][j] = 0.f;

    for (int k0 = 0; k0 < IN_FT; k0 += BK) {
        // stage seq tile, transposed to [k][node]
        for (int i = t; i < (BN * BK) / 4; i += 256) {
            int row = i >> 3;       // node within tile
            int c4  = i & 7;        // float4 within k-chunk
            int gn  = nodeBase + row;
            float4 v = make_float4(0.f, 0.f, 0.f, 0.f);
            if (gn < N) v = *(const float4*)(seq + (size_t)gn * IN_FT + k0 + c4 * 4);
            As[c4 * 4 + 0][row] = v.x;
            As[c4 * 4 + 1][row] = v.y;
            As[c4 * 4 + 2][row] = v.z;
            As[c4 * 4 + 3][row] = v.w;
        }
        // stage W tile, transposed to [k][feat]
        for (int i = t; i < (OUT_FT * BK) / 4; i += 256) {
            int row = i >> 3;       // output feature
            int c4  = i & 7;
            float4 v = *(const float4*)(W + (size_t)row * IN_FT + k0 + c4 * 4);
            Bs[c4 * 4 + 0][row] = v.x;
            Bs[c4 * 4 + 1][row] = v.y;
            Bs[c4 * 4 + 2][row] = v.z;
            Bs[c4 * 4 + 3][row] = v.w;
        }
        __syncthreads();
#pragma unroll
        for (int k = 0; k < BK; ++k) {
            float4 av = *(const float4*)&As[k][ty * 4];
            float4 bv = *(const float4*)&Bs[k][tx * 4];
            float a4[4] = {av.x, av.y, av.z, av.w};
            float b4[4] = {bv.x, bv.y, bv.z, bv.w};
#pragma unroll
            for (int i = 0; i < 4; ++i)
#pragma unroll
                for (int j = 0; j < 4; ++j)
                    acc[i][j] = fmaf(a4[i], b4[j], acc[i][j]);
        }
        __syncthreads();
    }
#pragma unroll
    for (int i = 0; i < 4; ++i) {
        int gn = nodeBase + ty * 4 + i;
        if (gn < N) {
            float4 o = make_float4(acc[i][0], acc[i][1], acc[i][2], acc[i][3]);
            *(float4*)(fts + (size_t)gn * OUT_FT + tx * 4) = o;
        }
    }
}

// ---------------------------------------------------------------------------
// CSR build: histogram by dst -> exclusive scan -> scatter (src,val) per dst
// ---------------------------------------------------------------------------
__global__ void zero2_i(int* __restrict__ a, int* __restrict__ b, int n) {
    int i = (int)blockIdx.x * 256 + (int)threadIdx.x;
    if (i < n) { a[i] = 0; b[i] = 0; }
}

__global__ void hist_kernel(const int* __restrict__ dst, int* __restrict__ counts, int E) {
    int e = (int)blockIdx.x * 256 + (int)threadIdx.x;
    if (e < E) atomicAdd(&counts[dst[e]], 1);
}

__global__ __launch_bounds__(1024) void scan_kernel(
    const int* __restrict__ counts, int* __restrict__ offsets, int N)
{
    __shared__ int sums[1024];
    const int t = (int)threadIdx.x;
    const int per = (N + 1023) / 1024;
    int start = t * per;
    int end   = min(start + per, N);
    int s = 0;
    for (int i = start; i < end; ++i) s += counts[i];
    sums[t] = s;
    __syncthreads();
    // Hillis-Steele inclusive scan over 1024 partials
    for (int d = 1; d < 1024; d <<= 1) {
        int v = (t >= d) ? sums[t - d] : 0;
        __syncthreads();
        sums[t] += v;
        __syncthreads();
    }
    int prefix = (t == 0) ? 0 : sums[t - 1];
    for (int i = start; i < end; ++i) { offsets[i] = prefix; prefix += counts[i]; }
    if (t == 0) offsets[N] = sums[1023];
}

__global__ void scatter_csr_kernel(
    const int* __restrict__ src, const int* __restrict__ dst,
    const float* __restrict__ val, const int* __restrict__ offsets,
    int* __restrict__ cursor, int* __restrict__ csr_src,
    float* __restrict__ csr_val, int E)
{
    int e = (int)blockIdx.x * 256 + (int)threadIdx.x;
    if (e < E) {
        int d = dst[e];
        int pos = offsets[d] + atomicAdd(&cursor[d], 1);
        csr_src[pos] = src[e];
        csr_val[pos] = val[e];
    }
}

// ---------------------------------------------------------------------------
// Gather-reduce: one wave per dst node, lane = output feature. Bias + PReLU.
// ---------------------------------------------------------------------------
__global__ __launch_bounds__(256) void gather_kernel(
    const float* __restrict__ fts, const int* __restrict__ offsets,
    const int* __restrict__ csr_src, const float* __restrict__ csr_val,
    const float* __restrict__ bias, const float* __restrict__ alpha,
    float* __restrict__ out, int N)
{
    int gtid = (int)blockIdx.x * 256 + (int)threadIdx.x;
    int node = gtid >> 6;
    int lane = gtid & 63;
    if (node >= N) return;
    int e0 = offsets[node];
    int e1 = offsets[node + 1];
    float acc = 0.f;
    for (int e = e0; e < e1; ++e) {
        int   s = csr_src[e];
        float v = csr_val[e];
        acc = fmaf(fts[(size_t)s * OUT_FT + lane], v, acc);
    }
    float o = acc + bias[lane];
    float a = alpha[0];
    out[(size_t)node * OUT_FT + lane] = (o >= 0.f) ? o : a * o;
}

// ---------------------------------------------------------------------------
// Fallback path (ws too small for CSR): direct atomic scatter into d_out
// ---------------------------------------------------------------------------
__global__ void zero_f(float* __restrict__ p, int n) {
    int i = (int)blockIdx.x * 256 + (int)threadIdx.x;
    if (i < n) p[i] = 0.f;
}

__global__ void scatter_atomic_kernel(
    const float* __restrict__ fts, const int* __restrict__ src,
    const int* __restrict__ dst, const float* __restrict__ val,
    float* __restrict__ out, int E)
{
    int tid = (int)blockIdx.x * 256 + (int)threadIdx.x;
    int e = tid >> 6;
    if (e >= E) return;
    int lane = tid & 63;
    float v = fts[(size_t)src[e] * OUT_FT + lane] * val[e];
    atomicAdd(out + (size_t)dst[e] * OUT_FT + lane, v);
}

__global__ void finalize_kernel(float* __restrict__ out, const float* __restrict__ bias,
                                const float* __restrict__ alpha, int n) {
    int i = (int)blockIdx.x * 256 + (int)threadIdx.x;
    if (i < n) {
        float o = out[i] + bias[i & (OUT_FT - 1)];
        out[i] = (o >= 0.f) ? o : alpha[0] * o;
    }
}

// ---------------------------------------------------------------------------
extern "C" void kernel_launch(void* const* d_in, const int* in_sizes, int n_in,
                              void* d_out, int out_size, void* d_ws, size_t ws_size,
                              hipStream_t stream) {
    const float* seq      = (const float*)d_in[0];
    const float* W        = (const float*)d_in[1];
    const float* bias     = (const float*)d_in[2];
    const float* alpha    = (const float*)d_in[3];
    const int*   edge_src = (const int*)d_in[4];
    const int*   edge_dst = (const int*)d_in[5];
    const float* edge_val = (const float*)d_in[6];
    float* out = (float*)d_out;

    const int N = in_sizes[0] / IN_FT;
    const int E = in_sizes[4];

    // carve workspace
    size_t off = 0;
    auto take = [&](size_t bytes) -> char* {
        char* p = (char*)d_ws + off;
        off += (bytes + 255) & ~(size_t)255;
        return p;
    };
    float* fts     = (float*)take((size_t)N * OUT_FT * sizeof(float));
    int*   counts  = (int*)take((size_t)N * sizeof(int));
    int*   offsets = (int*)take(((size_t)N + 1) * sizeof(int));
    int*   cursor  = (int*)take((size_t)N * sizeof(int));
    int*   csr_src = (int*)take((size_t)E * sizeof(int));
    float* csr_val = (float*)take((size_t)E * sizeof(float));
    const bool csr_ok = (off <= ws_size);

    const int gemm_blocks = (N + BN - 1) / BN;
    gemm_kernel<<<gemm_blocks, 256, 0, stream>>>(seq, W, fts, N);

    if (csr_ok) {
        zero2_i<<<(N + 255) / 256, 256, 0, stream>>>(counts, cursor, N);
        hist_kernel<<<(E + 255) / 256, 256, 0, stream>>>(edge_dst, counts, E);
        scan_kernel<<<1, 1024, 0, stream>>>(counts, offsets, N);
        scatter_csr_kernel<<<(E + 255) / 256, 256, 0, stream>>>(
            edge_src, edge_dst, edge_val, offsets, cursor, csr_src, csr_val, E);
        gather_kernel<<<((size_t)N * 64 + 255) / 256, 256, 0, stream>>>(
            fts, offsets, csr_src, csr_val, bias, alpha, out, N);
    } else {
        // atomic fallback: needs only fts in ws
        zero_f<<<((size_t)N * 64 + 255) / 256, 256, 0, stream>>>(out, N * OUT_FT);
        scatter_atomic_kernel<<<((size_t)E * 64 + 255) / 256, 256, 0, stream>>>(
            fts, edge_src, edge_dst, edge_val, out, E);
        finalize_kernel<<<((size_t)N * 64 + 255) / 256, 256, 0, stream>>>(
            out, bias, alpha, N * OUT_FT);
    }
}

// Round 2
// 305.812 us; speedup vs baseline: 1.1774x; 1.1774x over previous
//
#include <hip/hip_runtime.h>

#define IN_FT 256
#define OUT_FT 64

// ---------------------------------------------------------------------------
// GEMM: fts[N,64] = seq[N,256] @ W[64,256]^T   (fp32 vector ALU; no fp32 MFMA)
// Block = 256 threads computes 64 nodes x 64 feats; 4x4 register micro-tile.
// ---------------------------------------------------------------------------
constexpr int BN  = 64;   // nodes per block
constexpr int BK  = 32;   // k-chunk
constexpr int LDT = 68;   // padded LDS stride (floats)

__global__ __launch_bounds__(256) void gemm_kernel(
    const float* __restrict__ seq, const float* __restrict__ W,
    float* __restrict__ fts, int N)
{
    __shared__ float As[BK][LDT];   // [k][node]
    __shared__ float Bs[BK][LDT];   // [k][feat]
    const int t  = (int)threadIdx.x;
    const int tx = t & 15;          // feature quad
    const int ty = t >> 4;          // node quad
    const int nodeBase = (int)blockIdx.x * BN;

    float acc[4][4];
#pragma unroll
    for (int i = 0; i < 4; ++i)
#pragma unroll
        for (int j = 0; j < 4; ++j) acc[i][j] = 0.f;

    for (int k0 = 0; k0 < IN_FT; k0 += BK) {
        for (int i = t; i < (BN * BK) / 4; i += 256) {
            int row = i >> 3;
            int c4  = i & 7;
            int gn  = nodeBase + row;
            float4 v = make_float4(0.f, 0.f, 0.f, 0.f);
            if (gn < N) v = *(const float4*)(seq + (size_t)gn * IN_FT + k0 + c4 * 4);
            As[c4 * 4 + 0][row] = v.x;
            As[c4 * 4 + 1][row] = v.y;
            As[c4 * 4 + 2][row] = v.z;
            As[c4 * 4 + 3][row] = v.w;
        }
        for (int i = t; i < (OUT_FT * BK) / 4; i += 256) {
            int row = i >> 3;
            int c4  = i & 7;
            float4 v = *(const float4*)(W + (size_t)row * IN_FT + k0 + c4 * 4);
            Bs[c4 * 4 + 0][row] = v.x;
            Bs[c4 * 4 + 1][row] = v.y;
            Bs[c4 * 4 + 2][row] = v.z;
            Bs[c4 * 4 + 3][row] = v.w;
        }
        __syncthreads();
#pragma unroll
        for (int k = 0; k < BK; ++k) {
            float4 av = *(const float4*)&As[k][ty * 4];
            float4 bv = *(const float4*)&Bs[k][tx * 4];
            float a4[4] = {av.x, av.y, av.z, av.w};
            float b4[4] = {bv.x, bv.y, bv.z, bv.w};
#pragma unroll
            for (int i = 0; i < 4; ++i)
#pragma unroll
                for (int j = 0; j < 4; ++j)
                    acc[i][j] = fmaf(a4[i], b4[j], acc[i][j]);
        }
        __syncthreads();
    }
#pragma unroll
    for (int i = 0; i < 4; ++i) {
        int gn = nodeBase + ty * 4 + i;
        if (gn < N) {
            float4 o = make_float4(acc[i][0], acc[i][1], acc[i][2], acc[i][3]);
            *(float4*)(fts + (size_t)gn * OUT_FT + tx * 4) = o;
        }
    }
}

// ---------------------------------------------------------------------------
// CSR build: histogram -> hierarchical scan -> scatter
// ---------------------------------------------------------------------------
__global__ void zero2_i(int* __restrict__ a, int* __restrict__ b, int n) {
    int i = (int)blockIdx.x * 256 + (int)threadIdx.x;
    if (i < n) { a[i] = 0; b[i] = 0; }
}

__global__ void hist_kernel(const int* __restrict__ dst, int* __restrict__ counts, int E) {
    int e = (int)blockIdx.x * 256 + (int)threadIdx.x;
    if (e < E) atomicAdd(&counts[dst[e]], 1);
}

// exclusive prefix of v across 256 threads (returns exclusive sum)
__device__ __forceinline__ int block_excl_scan_256(int v, int t) {
    int lane = t & 63, wv = t >> 6;
    int incl = v;
#pragma unroll
    for (int d = 1; d < 64; d <<= 1) {
        int u = __shfl_up(incl, d, 64);
        if (lane >= d) incl += u;
    }
    __shared__ int wsum[4];
    if (lane == 63) wsum[wv] = incl;
    __syncthreads();
    int woff = 0;
    for (int i = 0; i < wv; ++i) woff += wsum[i];
    return woff + incl - v;
}

// phase 1: per-block (1024-elem chunk) sums, coalesced int4 loads
__global__ __launch_bounds__(256) void block_sum_kernel(
    const int* __restrict__ counts, int* __restrict__ blockSum, int N)
{
    const int t = (int)threadIdx.x;
    const int base = (int)blockIdx.x * 1024 + t * 4;
    int s = 0;
    if (base + 3 < N) {
        int4 v = *(const int4*)(counts + base);
        s = v.x + v.y + v.z + v.w;
    } else {
        for (int j = 0; j < 4; ++j) if (base + j < N) s += counts[base + j];
    }
    int lane = t & 63, wv = t >> 6;
#pragma unroll
    for (int d = 32; d >= 1; d >>= 1) s += __shfl_down(s, d, 64);
    __shared__ int wsum[4];
    if (lane == 0) wsum[wv] = s;
    __syncthreads();
    if (t == 0) blockSum[blockIdx.x] = wsum[0] + wsum[1] + wsum[2] + wsum[3];
}

// phase 2: scan block sums (NB <= 256), write offsets[N] = total
__global__ __launch_bounds__(256) void scan_blocks_kernel(
    const int* __restrict__ blockSum, int* __restrict__ blockOff,
    int* __restrict__ offsets, int NB, int N)
{
    const int t = (int)threadIdx.x;
    int v = (t < NB) ? blockSum[t] : 0;
    int excl = block_excl_scan_256(v, t);
    if (t < NB) blockOff[t] = excl;
    if (t == 255) offsets[N] = excl + v;   // grand total (v==0 here when NB<256)
}

// phase 3: per-chunk scan + write offsets, coalesced
__global__ __launch_bounds__(256) void scan_write_kernel(
    const int* __restrict__ counts, const int* __restrict__ blockOff,
    int* __restrict__ offsets, int N)
{
    const int t = (int)threadIdx.x;
    const int base = (int)blockIdx.x * 1024 + t * 4;
    int4 v = make_int4(0, 0, 0, 0);
    if (base + 3 < N) {
        v = *(const int4*)(counts + base);
    } else {
        if (base + 0 < N) v.x = counts[base + 0];
        if (base + 1 < N) v.y = counts[base + 1];
        if (base + 2 < N) v.z = counts[base + 2];
    }
    int s = v.x + v.y + v.z + v.w;
    int p = block_excl_scan_256(s, t) + blockOff[blockIdx.x];
    if (base + 0 < N) offsets[base + 0] = p;
    if (base + 1 < N) offsets[base + 1] = p + v.x;
    if (base + 2 < N) offsets[base + 2] = p + v.x + v.y;
    if (base + 3 < N) offsets[base + 3] = p + v.x + v.y + v.z;
}

__global__ void scatter_csr_kernel(
    const int* __restrict__ src, const int* __restrict__ dst,
    const float* __restrict__ val, const int* __restrict__ offsets,
    int* __restrict__ cursor, int* __restrict__ csr_src,
    float* __restrict__ csr_val, int E)
{
    int e = (int)blockIdx.x * 256 + (int)threadIdx.x;
    if (e < E) {
        int d = dst[e];
        int pos = offsets[d] + atomicAdd(&cursor[d], 1);
        csr_src[pos] = src[e];
        csr_val[pos] = val[e];
    }
}

// ---------------------------------------------------------------------------
// Gather-reduce: one wave per dst node, lane = output feature. Bias + PReLU.
// ---------------------------------------------------------------------------
__global__ __launch_bounds__(256) void gather_kernel(
    const float* __restrict__ fts, const int* __restrict__ offsets,
    const int* __restrict__ csr_src, const float* __restrict__ csr_val,
    const float* __restrict__ bias, const float* __restrict__ alpha,
    float* __restrict__ out, int N)
{
    int gtid = (int)blockIdx.x * 256 + (int)threadIdx.x;
    int node = gtid >> 6;
    int lane = gtid & 63;
    if (node >= N) return;
    int e0 = offsets[node];
    int e1 = offsets[node + 1];
    float acc = 0.f;
    for (int e = e0; e < e1; ++e) {
        int   s = csr_src[e];
        float v = csr_val[e];
        acc = fmaf(fts[(size_t)s * OUT_FT + lane], v, acc);
    }
    float o = acc + bias[lane];
    float a = alpha[0];
    out[(size_t)node * OUT_FT + lane] = (o >= 0.f) ? o : a * o;
}

// ---------------------------------------------------------------------------
// Fallback path (ws too small for CSR): direct atomic scatter into d_out
// ---------------------------------------------------------------------------
__global__ void zero_f(float* __restrict__ p, int n) {
    int i = (int)blockIdx.x * 256 + (int)threadIdx.x;
    if (i < n) p[i] = 0.f;
}

__global__ void scatter_atomic_kernel(
    const float* __restrict__ fts, const int* __restrict__ src,
    const int* __restrict__ dst, const float* __restrict__ val,
    float* __restrict__ out, int E)
{
    int tid = (int)blockIdx.x * 256 + (int)threadIdx.x;
    int e = tid >> 6;
    if (e >= E) return;
    int lane = tid & 63;
    float v = fts[(size_t)src[e] * OUT_FT + lane] * val[e];
    atomicAdd(out + (size_t)dst[e] * OUT_FT + lane, v);
}

__global__ void finalize_kernel(float* __restrict__ out, const float* __restrict__ bias,
                                const float* __restrict__ alpha, int n) {
    int i = (int)blockIdx.x * 256 + (int)threadIdx.x;
    if (i < n) {
        float o = out[i] + bias[i & (OUT_FT - 1)];
        out[i] = (o >= 0.f) ? o : alpha[0] * o;
    }
}

// ---------------------------------------------------------------------------
extern "C" void kernel_launch(void* const* d_in, const int* in_sizes, int n_in,
                              void* d_out, int out_size, void* d_ws, size_t ws_size,
                              hipStream_t stream) {
    const float* seq      = (const float*)d_in[0];
    const float* W        = (const float*)d_in[1];
    const float* bias     = (const float*)d_in[2];
    const float* alpha    = (const float*)d_in[3];
    const int*   edge_src = (const int*)d_in[4];
    const int*   edge_dst = (const int*)d_in[5];
    const float* edge_val = (const float*)d_in[6];
    float* out = (float*)d_out;

    const int N = in_sizes[0] / IN_FT;
    const int E = in_sizes[4];
    const int NB = (N + 1023) / 1024;   // scan chunks (<=256 supported)

    size_t off = 0;
    auto take = [&](size_t bytes) -> char* {
        char* p = (char*)d_ws + off;
        off += (bytes + 255) & ~(size_t)255;
        return p;
    };
    float* fts      = (float*)take((size_t)N * OUT_FT * sizeof(float));
    int*   counts   = (int*)take((size_t)N * sizeof(int));
    int*   offsets  = (int*)take(((size_t)N + 1) * sizeof(int));
    int*   cursor   = (int*)take((size_t)N * sizeof(int));
    int*   blockSum = (int*)take((size_t)NB * sizeof(int));
    int*   blockOff = (int*)take((size_t)NB * sizeof(int));
    int*   csr_src  = (int*)take((size_t)E * sizeof(int));
    float* csr_val  = (float*)take((size_t)E * sizeof(float));
    const bool csr_ok = (off <= ws_size) && (NB <= 256);

    const int gemm_blocks = (N + BN - 1) / BN;
    gemm_kernel<<<gemm_blocks, 256, 0, stream>>>(seq, W, fts, N);

    if (csr_ok) {
        zero2_i<<<(N + 255) / 256, 256, 0, stream>>>(counts, cursor, N);
        hist_kernel<<<(E + 255) / 256, 256, 0, stream>>>(edge_dst, counts, E);
        block_sum_kernel<<<NB, 256, 0, stream>>>(counts, blockSum, N);
        scan_blocks_kernel<<<1, 256, 0, stream>>>(blockSum, blockOff, offsets, NB, N);
        scan_write_kernel<<<NB, 256, 0, stream>>>(counts, blockOff, offsets, N);
        scatter_csr_kernel<<<(E + 255) / 256, 256, 0, stream>>>(
            edge_src, edge_dst, edge_val, offsets, cursor, csr_src, csr_val, E);
        gather_kernel<<<((size_t)N * 64 + 255) / 256, 256, 0, stream>>>(
            fts, offsets, csr_src, csr_val, bias, alpha, out, N);
    } else {
        zero_f<<<((size_t)N * 64 + 255) / 256, 256, 0, stream>>>(out, N * OUT_FT);
        scatter_atomic_kernel<<<((size_t)E * 64 + 255) / 256, 256, 0, stream>>>(
            fts, edge_src, edge_dst, edge_val, out, E);
        finalize_kernel<<<((size_t)N * 64 + 255) / 256, 256, 0, stream>>>(
            out, bias, alpha, N * OUT_FT);
    }
}

// Round 3
// 257.234 us; speedup vs baseline: 1.3998x; 1.1888x over previous
//
#include <hip/hip_runtime.h>

#define IN_FT 256
#define OUT_FT 64

// ---------------------------------------------------------------------------
// GEMM: fts[N,64] = seq[N,256] @ W[64,256]^T   (fp32 vector ALU; no fp32 MFMA)
// ---------------------------------------------------------------------------
constexpr int BN  = 64;   // nodes per block
constexpr int BK  = 32;   // k-chunk
constexpr int LDT = 68;   // padded LDS stride (floats)

__global__ __launch_bounds__(256) void gemm_kernel(
    const float* __restrict__ seq, const float* __restrict__ W,
    float* __restrict__ fts, int N)
{
    __shared__ float As[BK][LDT];   // [k][node]
    __shared__ float Bs[BK][LDT];   // [k][feat]
    const int t  = (int)threadIdx.x;
    const int tx = t & 15;
    const int ty = t >> 4;
    const int nodeBase = (int)blockIdx.x * BN;

    float acc[4][4];
#pragma unroll
    for (int i = 0; i < 4; ++i)
#pragma unroll
        for (int j = 0; j < 4; ++j) acc[i][j] = 0.f;

    for (int k0 = 0; k0 < IN_FT; k0 += BK) {
        for (int i = t; i < (BN * BK) / 4; i += 256) {
            int row = i >> 3;
            int c4  = i & 7;
            int gn  = nodeBase + row;
            float4 v = make_float4(0.f, 0.f, 0.f, 0.f);
            if (gn < N) v = *(const float4*)(seq + (size_t)gn * IN_FT + k0 + c4 * 4);
            As[c4 * 4 + 0][row] = v.x;
            As[c4 * 4 + 1][row] = v.y;
            As[c4 * 4 + 2][row] = v.z;
            As[c4 * 4 + 3][row] = v.w;
        }
        for (int i = t; i < (OUT_FT * BK) / 4; i += 256) {
            int row = i >> 3;
            int c4  = i & 7;
            float4 v = *(const float4*)(W + (size_t)row * IN_FT + k0 + c4 * 4);
            Bs[c4 * 4 + 0][row] = v.x;
            Bs[c4 * 4 + 1][row] = v.y;
            Bs[c4 * 4 + 2][row] = v.z;
            Bs[c4 * 4 + 3][row] = v.w;
        }
        __syncthreads();
#pragma unroll
        for (int k = 0; k < BK; ++k) {
            float4 av = *(const float4*)&As[k][ty * 4];
            float4 bv = *(const float4*)&Bs[k][tx * 4];
            float a4[4] = {av.x, av.y, av.z, av.w};
            float b4[4] = {bv.x, bv.y, bv.z, bv.w};
#pragma unroll
            for (int i = 0; i < 4; ++i)
#pragma unroll
                for (int j = 0; j < 4; ++j)
                    acc[i][j] = fmaf(a4[i], b4[j], acc[i][j]);
        }
        __syncthreads();
    }
#pragma unroll
    for (int i = 0; i < 4; ++i) {
        int gn = nodeBase + ty * 4 + i;
        if (gn < N) {
            float4 o = make_float4(acc[i][0], acc[i][1], acc[i][2], acc[i][3]);
            *(float4*)(fts + (size_t)gn * OUT_FT + tx * 4) = o;
        }
    }
}

// ---------------------------------------------------------------------------
// CSR build: histogram -> hierarchical scan -> scatter
// ---------------------------------------------------------------------------
__global__ void zero2_i(int* __restrict__ a, int* __restrict__ b, int n) {
    int i = (int)blockIdx.x * 256 + (int)threadIdx.x;
    if (i < n) { a[i] = 0; b[i] = 0; }
}

__global__ void hist_kernel(const int* __restrict__ dst, int* __restrict__ counts, int E) {
    int e = (int)blockIdx.x * 256 + (int)threadIdx.x;
    if (e < E) atomicAdd(&counts[dst[e]], 1);
}

__device__ __forceinline__ int block_excl_scan_256(int v, int t) {
    int lane = t & 63, wv = t >> 6;
    int incl = v;
#pragma unroll
    for (int d = 1; d < 64; d <<= 1) {
        int u = __shfl_up(incl, d, 64);
        if (lane >= d) incl += u;
    }
    __shared__ int wsum[4];
    if (lane == 63) wsum[wv] = incl;
    __syncthreads();
    int woff = 0;
    for (int i = 0; i < wv; ++i) woff += wsum[i];
    return woff + incl - v;
}

__global__ __launch_bounds__(256) void block_sum_kernel(
    const int* __restrict__ counts, int* __restrict__ blockSum, int N)
{
    const int t = (int)threadIdx.x;
    const int base = (int)blockIdx.x * 1024 + t * 4;
    int s = 0;
    if (base + 3 < N) {
        int4 v = *(const int4*)(counts + base);
        s = v.x + v.y + v.z + v.w;
    } else {
        for (int j = 0; j < 4; ++j) if (base + j < N) s += counts[base + j];
    }
    int lane = t & 63, wv = t >> 6;
#pragma unroll
    for (int d = 32; d >= 1; d >>= 1) s += __shfl_down(s, d, 64);
    __shared__ int wsum[4];
    if (lane == 0) wsum[wv] = s;
    __syncthreads();
    if (t == 0) blockSum[blockIdx.x] = wsum[0] + wsum[1] + wsum[2] + wsum[3];
}

__global__ __launch_bounds__(256) void scan_blocks_kernel(
    const int* __restrict__ blockSum, int* __restrict__ blockOff,
    int* __restrict__ offsets, int NB, int N)
{
    const int t = (int)threadIdx.x;
    int v = (t < NB) ? blockSum[t] : 0;
    int excl = block_excl_scan_256(v, t);
    if (t < NB) blockOff[t] = excl;
    if (t == 255) offsets[N] = excl + v;
}

__global__ __launch_bounds__(256) void scan_write_kernel(
    const int* __restrict__ counts, const int* __restrict__ blockOff,
    int* __restrict__ offsets, int N)
{
    const int t = (int)threadIdx.x;
    const int base = (int)blockIdx.x * 1024 + t * 4;
    int4 v = make_int4(0, 0, 0, 0);
    if (base + 3 < N) {
        v = *(const int4*)(counts + base);
    } else {
        if (base + 0 < N) v.x = counts[base + 0];
        if (base + 1 < N) v.y = counts[base + 1];
        if (base + 2 < N) v.z = counts[base + 2];
    }
    int s = v.x + v.y + v.z + v.w;
    int p = block_excl_scan_256(s, t) + blockOff[blockIdx.x];
    if (base + 0 < N) offsets[base + 0] = p;
    if (base + 1 < N) offsets[base + 1] = p + v.x;
    if (base + 2 < N) offsets[base + 2] = p + v.x + v.y;
    if (base + 3 < N) offsets[base + 3] = p + v.x + v.y + v.z;
}

__global__ void scatter_csr_kernel(
    const int* __restrict__ src, const int* __restrict__ dst,
    const float* __restrict__ val, const int* __restrict__ offsets,
    int* __restrict__ cursor, int* __restrict__ csr_src,
    float* __restrict__ csr_val, int E)
{
    int e = (int)blockIdx.x * 256 + (int)threadIdx.x;
    if (e < E) {
        int d = dst[e];
        int pos = offsets[d] + atomicAdd(&cursor[d], 1);
        csr_src[pos] = src[e];
        csr_val[pos] = val[e];
    }
}

// ---------------------------------------------------------------------------
// Gather-reduce: one wave per dst node, lane = output feature.
// Indices staged cooperatively (one coalesced load per <=64 edges), broadcast
// via shfl; fts gathers issued 4-deep for memory-level parallelism.
// ---------------------------------------------------------------------------
__global__ __launch_bounds__(256) void gather_kernel(
    const float* __restrict__ fts, const int* __restrict__ offsets,
    const int* __restrict__ csr_src, const float* __restrict__ csr_val,
    const float* __restrict__ bias, const float* __restrict__ alpha,
    float* __restrict__ out, int N)
{
    int gtid = (int)blockIdx.x * 256 + (int)threadIdx.x;
    int node = gtid >> 6;
    int lane = gtid & 63;
    if (node >= N) return;
    int e0 = offsets[node];
    int deg = offsets[node + 1] - e0;
    float acc = 0.f;

    for (int base = 0; base < deg; base += 64) {
        int rem = deg - base;
        int cnt = rem < 64 ? rem : 64;
        // cooperative stage: lane i holds edge (base+i)'s src & val
        int   sReg = 0;
        float vReg = 0.f;
        if (lane < cnt) {
            sReg = csr_src[e0 + base + lane];
            vReg = csr_val[e0 + base + lane];
        }
        int j = 0;
        for (; j + 4 <= cnt; j += 4) {
            int   s0 = __shfl(sReg, j + 0, 64);
            int   s1 = __shfl(sReg, j + 1, 64);
            int   s2 = __shfl(sReg, j + 2, 64);
            int   s3 = __shfl(sReg, j + 3, 64);
            float v0 = __shfl(vReg, j + 0, 64);
            float v1 = __shfl(vReg, j + 1, 64);
            float v2 = __shfl(vReg, j + 2, 64);
            float v3 = __shfl(vReg, j + 3, 64);
            float f0 = fts[(size_t)s0 * OUT_FT + lane];
            float f1 = fts[(size_t)s1 * OUT_FT + lane];
            float f2 = fts[(size_t)s2 * OUT_FT + lane];
            float f3 = fts[(size_t)s3 * OUT_FT + lane];
            acc = fmaf(f0, v0, acc);
            acc = fmaf(f1, v1, acc);
            acc = fmaf(f2, v2, acc);
            acc = fmaf(f3, v3, acc);
        }
        for (; j < cnt; ++j) {
            int   sj = __shfl(sReg, j, 64);
            float vj = __shfl(vReg, j, 64);
            acc = fmaf(fts[(size_t)sj * OUT_FT + lane], vj, acc);
        }
    }
    float o = acc + bias[lane];
    float a = alpha[0];
    out[(size_t)node * OUT_FT + lane] = (o >= 0.f) ? o : a * o;
}

// ---------------------------------------------------------------------------
// Fallback path (ws too small for CSR)
// ---------------------------------------------------------------------------
__global__ void zero_f(float* __restrict__ p, int n) {
    int i = (int)blockIdx.x * 256 + (int)threadIdx.x;
    if (i < n) p[i] = 0.f;
}

__global__ void scatter_atomic_kernel(
    const float* __restrict__ fts, const int* __restrict__ src,
    const int* __restrict__ dst, const float* __restrict__ val,
    float* __restrict__ out, int E)
{
    int tid = (int)blockIdx.x * 256 + (int)threadIdx.x;
    int e = tid >> 6;
    if (e >= E) return;
    int lane = tid & 63;
    float v = fts[(size_t)src[e] * OUT_FT + lane] * val[e];
    atomicAdd(out + (size_t)dst[e] * OUT_FT + lane, v);
}

__global__ void finalize_kernel(float* __restrict__ out, const float* __restrict__ bias,
                                const float* __restrict__ alpha, int n) {
    int i = (int)blockIdx.x * 256 + (int)threadIdx.x;
    if (i < n) {
        float o = out[i] + bias[i & (OUT_FT - 1)];
        out[i] = (o >= 0.f) ? o : alpha[0] * o;
    }
}

// ---------------------------------------------------------------------------
extern "C" void kernel_launch(void* const* d_in, const int* in_sizes, int n_in,
                              void* d_out, int out_size, void* d_ws, size_t ws_size,
                              hipStream_t stream) {
    const float* seq      = (const float*)d_in[0];
    const float* W        = (const float*)d_in[1];
    const float* bias     = (const float*)d_in[2];
    const float* alpha    = (const float*)d_in[3];
    const int*   edge_src = (const int*)d_in[4];
    const int*   edge_dst = (const int*)d_in[5];
    const float* edge_val = (const float*)d_in[6];
    float* out = (float*)d_out;

    const int N = in_sizes[0] / IN_FT;
    const int E = in_sizes[4];
    const int NB = (N + 1023) / 1024;

    size_t off = 0;
    auto take = [&](size_t bytes) -> char* {
        char* p = (char*)d_ws + off;
        off += (bytes + 255) & ~(size_t)255;
        return p;
    };
    float* fts      = (float*)take((size_t)N * OUT_FT * sizeof(float));
    int*   counts   = (int*)take((size_t)N * sizeof(int));
    int*   offsets  = (int*)take(((size_t)N + 1) * sizeof(int));
    int*   cursor   = (int*)take((size_t)N * sizeof(int));
    int*   blockSum = (int*)take((size_t)NB * sizeof(int));
    int*   blockOff = (int*)take((size_t)NB * sizeof(int));
    int*   csr_src  = (int*)take((size_t)E * sizeof(int));
    float* csr_val  = (float*)take((size_t)E * sizeof(float));
    const bool csr_ok = (off <= ws_size) && (NB <= 256);

    const int gemm_blocks = (N + BN - 1) / BN;
    gemm_kernel<<<gemm_blocks, 256, 0, stream>>>(seq, W, fts, N);

    if (csr_ok) {
        zero2_i<<<(N + 255) / 256, 256, 0, stream>>>(counts, cursor, N);
        hist_kernel<<<(E + 255) / 256, 256, 0, stream>>>(edge_dst, counts, E);
        block_sum_kernel<<<NB, 256, 0, stream>>>(counts, blockSum, N);
        scan_blocks_kernel<<<1, 256, 0, stream>>>(blockSum, blockOff, offsets, NB, N);
        scan_write_kernel<<<NB, 256, 0, stream>>>(counts, blockOff, offsets, N);
        scatter_csr_kernel<<<(E + 255) / 256, 256, 0, stream>>>(
            edge_src, edge_dst, edge_val, offsets, cursor, csr_src, csr_val, E);
        gather_kernel<<<((size_t)N * 64 + 255) / 256, 256, 0, stream>>>(
            fts, offsets, csr_src, csr_val, bias, alpha, out, N);
    } else {
        zero_f<<<((size_t)N * 64 + 255) / 256, 256, 0, stream>>>(out, N * OUT_FT);
        scatter_atomic_kernel<<<((size_t)E * 64 + 255) / 256, 256, 0, stream>>>(
            fts, edge_src, edge_dst, edge_val, out, E);
        finalize_kernel<<<((size_t)N * 64 + 255) / 256, 256, 0, stream>>>(
            out, bias, alpha, N * OUT_FT);
    }
}